// Round 6
// baseline (623.013 us; speedup 1.0000x reference)
//
#include <hip/hip_runtime.h>
#include <hip/hip_bf16.h>
#include <stdint.h>

// Problem constants (B=2, L=2048 -> T=4096 tokens)
#define T_TOK 4096
#define DDIM  1024
#define IDIM  4096
#define NEXP  8
// padded row count for gathered matrices (worst-case tile overhang)
#define GROWS (T_TOK*2 + 128)

typedef __attribute__((ext_vector_type(8))) short bfrag;   // 8 bf16 (4 VGPR)
typedef __attribute__((ext_vector_type(4))) float f32x4;   // MFMA accum

__device__ __forceinline__ unsigned short f2bf(float x) {
    unsigned int u = __float_as_uint(x);
    unsigned int r = u + 0x7FFFu + ((u >> 16) & 1u);   // RNE
    return (unsigned short)(r >> 16);
}
__device__ __forceinline__ float bf2f(unsigned short h) {
    return __uint_as_float(((unsigned int)h) << 16);
}

// async global->LDS, 16B per lane; LDS base must be wave-uniform
#define GLOAD16(gsrc, ldst)                                                     \
    __builtin_amdgcn_global_load_lds(                                           \
        (const __attribute__((address_space(1))) unsigned int*)(gsrc),          \
        (__attribute__((address_space(3))) unsigned int*)(ldst), 16, 0, 0)

// ---------------------------------------------------------------------------
// K1: per-token layernorm stats + xhat (bf16), fp32 router logits, top-2,
//     softmax -> per-slot weights; builds per-expert token lists via atomics.
// ---------------------------------------------------------------------------
__global__ __launch_bounds__(256) void router_kernel(
    const float* __restrict__ x,
    const float* __restrict__ rng, const float* __restrict__ rnb,
    const float* __restrict__ rw,  const float* __restrict__ rb,
    unsigned short* __restrict__ xhat,
    int* __restrict__ counts, int* __restrict__ tok_slot,
    float* __restrict__ wslot)
{
    const int t = blockIdx.x;
    const int tid = threadIdx.x;
    const int lane = tid & 63, wid = tid >> 6;

    float4 v = *(const float4*)(x + (size_t)t * DDIM + tid * 4);
    float s1 = v.x + v.y + v.z + v.w;
    float s2 = v.x*v.x + v.y*v.y + v.z*v.z + v.w*v.w;
    #pragma unroll
    for (int m = 32; m; m >>= 1) { s1 += __shfl_xor(s1, m, 64); s2 += __shfl_xor(s2, m, 64); }

    __shared__ float red[8];
    __shared__ float pl[4][8];
    __shared__ float bcast[2];
    if (lane == 0) { red[wid] = s1; red[wid + 4] = s2; }
    __syncthreads();
    if (tid == 0) {
        float S1 = red[0] + red[1] + red[2] + red[3];
        float S2 = red[4] + red[5] + red[6] + red[7];
        float mean = S1 * (1.f / 1024.f);
        float var  = S2 * (1.f / 1024.f) - mean * mean;
        bcast[0] = mean; bcast[1] = rsqrtf(var + 1e-5f);
    }
    __syncthreads();
    const float mean = bcast[0], rinv = bcast[1];

    float4 xh = { (v.x - mean) * rinv, (v.y - mean) * rinv,
                  (v.z - mean) * rinv, (v.w - mean) * rinv };
    ushort4 hx = { f2bf(xh.x), f2bf(xh.y), f2bf(xh.z), f2bf(xh.w) };
    *(ushort4*)(xhat + (size_t)t * DDIM + tid * 4) = hx;

    // router layernorm affine + logits (kept fp32 to match reference top-k)
    float4 g = *(const float4*)(rng + tid * 4);
    float4 b = *(const float4*)(rnb + tid * 4);
    float4 nm = { xh.x*g.x + b.x, xh.y*g.y + b.y, xh.z*g.z + b.z, xh.w*g.w + b.w };
    float p[8];
    #pragma unroll
    for (int e = 0; e < 8; e++) {
        float4 w = *(const float4*)(rw + e * DDIM + tid * 4);
        p[e] = nm.x*w.x + nm.y*w.y + nm.z*w.z + nm.w*w.w;
    }
    #pragma unroll
    for (int m = 32; m; m >>= 1) {
        #pragma unroll
        for (int e = 0; e < 8; e++) p[e] += __shfl_xor(p[e], m, 64);
    }
    if (lane == 0) {
        #pragma unroll
        for (int e = 0; e < 8; e++) pl[wid][e] = p[e];
    }
    __syncthreads();
    if (tid == 0) {
        float l[8];
        #pragma unroll
        for (int e = 0; e < 8; e++) l[e] = pl[0][e] + pl[1][e] + pl[2][e] + pl[3][e] + rb[e];
        int e0 = 0; float v0 = l[0];
        for (int e = 1; e < 8; e++) if (l[e] > v0) { v0 = l[e]; e0 = e; }
        int e1 = (e0 == 0) ? 1 : 0; float v1 = l[e1];
        for (int e = 0; e < 8; e++) if (e != e0 && l[e] > v1) { v1 = l[e]; e1 = e; }
        float ex = expf(v1 - v0);
        float w0 = 1.f / (1.f + ex);
        float w1 = ex * w0;
        int p0 = atomicAdd(&counts[e0], 1);
        tok_slot[e0 * T_TOK + p0] = (t << 1);
        int p1 = atomicAdd(&counts[e1], 1);
        tok_slot[e1 * T_TOK + p1] = (t << 1) | 1;
        wslot[t * 2]     = w0;
        wslot[t * 2 + 1] = w1;
    }
}

// K2: tiny exclusive prefix over 8 expert counts
__global__ void prefix_kernel(const int* __restrict__ counts, int* __restrict__ offs)
{
    if (threadIdx.x == 0) {
        int a = 0;
        for (int e = 0; e < 8; e++) { offs[e] = a; a += counts[e]; }
    }
}

// ---------------------------------------------------------------------------
// K3: build compacted per-expert A matrix: Agath[off[e]+pos][d] =
//     bf16( xhat[t][d]*ln_g[e][d] + ln_b[e][d] ), plus rowinfo for scatter.
// ---------------------------------------------------------------------------
__global__ __launch_bounds__(256) void gather_kernel(
    const unsigned short* __restrict__ xhat,
    const float* __restrict__ lng, const float* __restrict__ lnb,
    const int* __restrict__ counts, const int* __restrict__ offs,
    const int* __restrict__ tok_slot,
    unsigned short* __restrict__ Agath, int* __restrict__ rowinfo)
{
    const int e = blockIdx.y, pos = blockIdx.x;
    if (pos >= counts[e]) return;
    const int grow = offs[e] + pos;
    const int info = tok_slot[e * T_TOK + pos];
    if (threadIdx.x == 0) rowinfo[grow] = info;
    const int t = info >> 1;
    const int d = threadIdx.x * 4;
    ushort4 hx = *(const ushort4*)(xhat + (size_t)t * DDIM + d);
    float4 g = *(const float4*)(lng + (size_t)e * DDIM + d);
    float4 b = *(const float4*)(lnb + (size_t)e * DDIM + d);
    ushort4 o = { f2bf(bf2f(hx.x) * g.x + b.x),
                  f2bf(bf2f(hx.y) * g.y + b.y),
                  f2bf(bf2f(hx.z) * g.z + b.z),
                  f2bf(bf2f(hx.w) * g.w + b.w) };
    *(ushort4*)(Agath + (size_t)grow * DDIM + d) = o;
}

// ---------------------------------------------------------------------------
// K4: transpose+convert weights: W [E][Kd][Nd] fp32 -> WT [E][Nd][Kd] bf16.
// Block = 256 threads, tile = 256 n-cols x 64 k-rows. Reads coalesced along n
// (256B/row-pass); each thread then owns one full 128B output line.
// ---------------------------------------------------------------------------
__global__ __launch_bounds__(256) void transpose_kernel(
    const float* __restrict__ W, unsigned short* __restrict__ WT,
    int Kd, int Nd)
{
    const int e  = blockIdx.z;
    const int k0 = blockIdx.y * 64;
    const int n  = blockIdx.x * 256 + threadIdx.x;
    const float* src = W + (size_t)e * Kd * Nd + (size_t)k0 * Nd + n;
    unsigned short* dst = WT + ((size_t)e * Nd + n) * Kd + k0;
    unsigned short buf[64];
    #pragma unroll
    for (int j = 0; j < 64; j++)
        buf[j] = f2bf(src[(size_t)j * Nd]);
    #pragma unroll
    for (int c = 0; c < 8; c++)
        *(int4*)(dst + c * 8) = *(const int4*)(buf + c * 8);
}

// ---------------------------------------------------------------------------
// GEMM (m97 structure): C[128x128] tile, BK=64, 4 waves x (64x64) sub-tile.
// A [*][Kd] bf16 rows, B = WT [E][Nd][Kd] bf16 rows — both staged with
// global_load_lds width=16 into linear LDS [128][64] (no pad; residual
// fragment-read bank conflicts are known-benign at this structure).
// EPI=0: +b1, exact GELU -> H (bf16). EPI=1: +b2, *combine-w, atomicAdd out.
// ---------------------------------------------------------------------------
template<int EPI>
__global__ __launch_bounds__(256) void gemm_kernel(
    const unsigned short* __restrict__ Asrc,
    const unsigned short* __restrict__ Bsrc,
    const float* __restrict__ bias,
    const int* __restrict__ counts,
    const int* __restrict__ offs,
    const int* __restrict__ rowinfo,
    const float* __restrict__ wslot,
    unsigned short* __restrict__ Hout,
    float* __restrict__ Out,
    int Kd, int Nd)
{
    const int e  = blockIdx.z;
    const int ne = counts[e];
    const int mt = blockIdx.y;
    if (mt * 128 >= ne) return;
    const int n0 = blockIdx.x * 128;
    const int growbase = offs[e] + mt * 128;
    const int tid  = threadIdx.x;
    const int lane = tid & 63;
    const int wm = (tid >> 7) & 1;
    const int wn = (tid >> 6) & 1;

    __shared__ unsigned short As[128 * 64];
    __shared__ unsigned short Bs[128 * 64];

    f32x4 acc[4][4];
    #pragma unroll
    for (int i = 0; i < 4; i++)
        #pragma unroll
        for (int j = 0; j < 4; j++)
            acc[i][j] = (f32x4){0.f, 0.f, 0.f, 0.f};

    // staging: thread tid covers (row = c*32 + tid/8, kchunk = tid%8)
    const unsigned short* ap = Asrc + (size_t)(growbase + (tid >> 3)) * Kd + (tid & 7) * 8;
    const unsigned short* bp = Bsrc + ((size_t)e * Nd + n0 + (tid >> 3)) * Kd + (tid & 7) * 8;
    char* aldsw = (char*)As + (tid >> 6) * 1024;   // wave-uniform base
    char* bldsw = (char*)Bs + (tid >> 6) * 1024;
    const size_t rowstep = (size_t)32 * Kd;

    for (int k0 = 0; k0 < Kd; k0 += 64) {
        __syncthreads();                 // previous compute done -> safe to overwrite
        #pragma unroll
        for (int c = 0; c < 4; c++) {
            GLOAD16(ap + c * rowstep, aldsw + c * 4096);
            GLOAD16(bp + c * rowstep, bldsw + c * 4096);
        }
        ap += 64; bp += 64;
        __syncthreads();                 // loads landed (barrier drains vmcnt)
        #pragma unroll
        for (int kk = 0; kk < 2; kk++) {
            bfrag av[4], bv[4];
            #pragma unroll
            for (int i = 0; i < 4; i++)
                av[i] = *(const bfrag*)((const char*)As +
                         (wm * 64 + i * 16 + (lane & 15)) * 128 + kk * 64 + ((lane >> 4) << 4));
            #pragma unroll
            for (int j = 0; j < 4; j++)
                bv[j] = *(const bfrag*)((const char*)Bs +
                         (wn * 64 + j * 16 + (lane & 15)) * 128 + kk * 64 + ((lane >> 4) << 4));
            #pragma unroll
            for (int i = 0; i < 4; i++)
                #pragma unroll
                for (int j = 0; j < 4; j++)
                    acc[i][j] = __builtin_amdgcn_mfma_f32_16x16x32_bf16(av[i], bv[j], acc[i][j], 0, 0, 0);
        }
    }

    // ---- epilogue (C/D layout: col = lane&15, row = (lane>>4)*4 + reg) ----
    const float* bg = bias + (size_t)e * Nd;
    #pragma unroll
    for (int i = 0; i < 4; i++) {
        #pragma unroll
        for (int r = 0; r < 4; r++) {
            int mrow = wm * 64 + i * 16 + ((lane >> 4) << 2) + r;
            int pos = mt * 128 + mrow;
            if (pos >= ne) continue;
            if constexpr (EPI == 0) {
                size_t rowoff = (size_t)(growbase + mrow) * Nd;
                #pragma unroll
                for (int j = 0; j < 4; j++) {
                    int col = n0 + wn * 64 + j * 16 + (lane & 15);
                    float y = acc[i][j][r] + bg[col];
                    float gl = 0.5f * y * (1.f + erff(y * 0.70710678118654752f));
                    Hout[rowoff + col] = f2bf(gl);
                }
            } else {
                int info = rowinfo[growbase + mrow];
                float wg = wslot[info];
                float* op = Out + (size_t)(info >> 1) * Nd;
                #pragma unroll
                for (int j = 0; j < 4; j++) {
                    int col = n0 + wn * 64 + j * 16 + (lane & 15);
                    float y = acc[i][j][r] + bg[col];
                    atomicAdd(op + col, wg * y);   // exactly 2 adds/elem -> deterministic
                }
            }
        }
    }
}

// ---------------------------------------------------------------------------
extern "C" void kernel_launch(void* const* d_in, const int* in_sizes, int n_in,
                              void* d_out, int out_size, void* d_ws, size_t ws_size,
                              hipStream_t stream)
{
    (void)in_sizes; (void)n_in;
    const float* hidden   = (const float*)d_in[0];
    const float* rn_g     = (const float*)d_in[1];
    const float* rn_b     = (const float*)d_in[2];
    const float* router_w = (const float*)d_in[3];
    const float* router_b = (const float*)d_in[4];
    const float* ln_g     = (const float*)d_in[5];
    const float* ln_b     = (const float*)d_in[6];
    const float* w1       = (const float*)d_in[7];
    const float* b1       = (const float*)d_in[8];
    const float* w2       = (const float*)d_in[9];
    const float* b2       = (const float*)d_in[10];
    float* out = (float*)d_out;

    // workspace layout (bytes), total ~160.9 MB
    //   xhat   @ 0           :  8,388,608  (4096 x 1024 bf16)
    //   Agath  @ 8,388,608   : 17,039,360  (8320 x 1024 bf16)
    //   H      @ 25,427,968  : 68,157,440  (8320 x 4096 bf16)
    //   WT     @ 93,585,408  : 67,108,864  (W1T, then reused for W2T)
    //   counts @ 160,694,272 / offs / tok_slot / rowinfo / wslot
    char* ws = (char*)d_ws;
    unsigned short* xhat   = (unsigned short*)ws;
    unsigned short* Agath  = (unsigned short*)(ws + 8388608);
    unsigned short* H      = (unsigned short*)(ws + 25427968);
    unsigned short* WT     = (unsigned short*)(ws + 93585408);
    int*   counts   = (int*)(ws + 160694272);
    int*   offs     = (int*)(ws + 160694304);
    int*   tok_slot = (int*)(ws + 160694336);
    int*   rowinfo  = (int*)(ws + 160825408);
    float* wslot    = (float*)(ws + 160858688);
    if (ws_size < 160891456) return;   // fail loudly (validation will catch it)

    hipMemsetAsync(counts, 0, 64, stream);                 // counts + offs
    hipMemsetAsync(d_out, 0, (size_t)out_size * sizeof(float), stream);

    // W1 [8][1024][4096] -> W1T [8][4096][1024]
    transpose_kernel<<<dim3(IDIM / 256, DDIM / 64, NEXP), 256, 0, stream>>>(w1, WT, DDIM, IDIM);
    router_kernel<<<T_TOK, 256, 0, stream>>>(hidden, rn_g, rn_b, router_w, router_b,
                                             xhat, counts, tok_slot, wslot);
    prefix_kernel<<<1, 64, 0, stream>>>(counts, offs);
    gather_kernel<<<dim3(T_TOK, NEXP), 256, 0, stream>>>(xhat, ln_g, ln_b, counts, offs,
                                                         tok_slot, Agath, rowinfo);
    // GEMM1: [rows x 1024] x [1024 x 4096] + b1, GELU -> H
    gemm_kernel<0><<<dim3(IDIM / 128, 32, NEXP), 256, 0, stream>>>(
        Agath, WT, b1, counts, offs, rowinfo, wslot, H, nullptr, DDIM, IDIM);
    // W2 [8][4096][1024] -> W2T [8][1024][4096] (reuses WT buffer after GEMM1)
    transpose_kernel<<<dim3(DDIM / 256, IDIM / 64, NEXP), 256, 0, stream>>>(w2, WT, IDIM, DDIM);
    // GEMM2: [rows x 4096] x [4096 x 1024] + b2, *w, scatter-add -> out
    gemm_kernel<1><<<dim3(DDIM / 128, 32, NEXP), 256, 0, stream>>>(
        H, WT, b2, counts, offs, rowinfo, wslot, nullptr, out, IDIM, DDIM);
}

// Round 7
// 614.838 us; speedup vs baseline: 1.0133x; 1.0133x over previous
//
#include <hip/hip_runtime.h>
#include <hip/hip_bf16.h>
#include <stdint.h>

// Problem constants (B=2, L=2048 -> T=4096 tokens)
#define T_TOK 4096
#define DDIM  1024
#define IDIM  4096
#define NEXP  8
// padded row count for gathered matrices (worst-case tile overhang)
#define GROWS (T_TOK*2 + 128)

typedef __attribute__((ext_vector_type(8))) short bfrag;   // 8 bf16 (4 VGPR)
typedef __attribute__((ext_vector_type(4))) float f32x4;   // MFMA accum

__device__ __forceinline__ unsigned short f2bf(float x) {
    unsigned int u = __float_as_uint(x);
    unsigned int r = u + 0x7FFFu + ((u >> 16) & 1u);   // RNE
    return (unsigned short)(r >> 16);
}
__device__ __forceinline__ float bf2f(unsigned short h) {
    return __uint_as_float(((unsigned int)h) << 16);
}

// async global->LDS, 16B per lane; LDS base must be wave-uniform
#define GLOAD16(gsrc, ldst)                                                     \
    __builtin_amdgcn_global_load_lds(                                           \
        (const __attribute__((address_space(1))) unsigned int*)(gsrc),          \
        (__attribute__((address_space(3))) unsigned int*)(ldst), 16, 0, 0)

// ---------------------------------------------------------------------------
// K1: per-token layernorm stats + xhat (bf16), fp32 router logits, top-2,
//     softmax -> per-slot weights; builds per-expert token lists via atomics.
// ---------------------------------------------------------------------------
__global__ __launch_bounds__(256) void router_kernel(
    const float* __restrict__ x,
    const float* __restrict__ rng, const float* __restrict__ rnb,
    const float* __restrict__ rw,  const float* __restrict__ rb,
    unsigned short* __restrict__ xhat,
    int* __restrict__ counts, int* __restrict__ tok_slot,
    float* __restrict__ wslot)
{
    const int t = blockIdx.x;
    const int tid = threadIdx.x;
    const int lane = tid & 63, wid = tid >> 6;

    float4 v = *(const float4*)(x + (size_t)t * DDIM + tid * 4);
    float s1 = v.x + v.y + v.z + v.w;
    float s2 = v.x*v.x + v.y*v.y + v.z*v.z + v.w*v.w;
    #pragma unroll
    for (int m = 32; m; m >>= 1) { s1 += __shfl_xor(s1, m, 64); s2 += __shfl_xor(s2, m, 64); }

    __shared__ float red[8];
    __shared__ float pl[4][8];
    __shared__ float bcast[2];
    if (lane == 0) { red[wid] = s1; red[wid + 4] = s2; }
    __syncthreads();
    if (tid == 0) {
        float S1 = red[0] + red[1] + red[2] + red[3];
        float S2 = red[4] + red[5] + red[6] + red[7];
        float mean = S1 * (1.f / 1024.f);
        float var  = S2 * (1.f / 1024.f) - mean * mean;
        bcast[0] = mean; bcast[1] = rsqrtf(var + 1e-5f);
    }
    __syncthreads();
    const float mean = bcast[0], rinv = bcast[1];

    float4 xh = { (v.x - mean) * rinv, (v.y - mean) * rinv,
                  (v.z - mean) * rinv, (v.w - mean) * rinv };
    ushort4 hx = { f2bf(xh.x), f2bf(xh.y), f2bf(xh.z), f2bf(xh.w) };
    *(ushort4*)(xhat + (size_t)t * DDIM + tid * 4) = hx;

    // router layernorm affine + logits (kept fp32 to match reference top-k)
    float4 g = *(const float4*)(rng + tid * 4);
    float4 b = *(const float4*)(rnb + tid * 4);
    float4 nm = { xh.x*g.x + b.x, xh.y*g.y + b.y, xh.z*g.z + b.z, xh.w*g.w + b.w };
    float p[8];
    #pragma unroll
    for (int e = 0; e < 8; e++) {
        float4 w = *(const float4*)(rw + e * DDIM + tid * 4);
        p[e] = nm.x*w.x + nm.y*w.y + nm.z*w.z + nm.w*w.w;
    }
    #pragma unroll
    for (int m = 32; m; m >>= 1) {
        #pragma unroll
        for (int e = 0; e < 8; e++) p[e] += __shfl_xor(p[e], m, 64);
    }
    if (lane == 0) {
        #pragma unroll
        for (int e = 0; e < 8; e++) pl[wid][e] = p[e];
    }
    __syncthreads();
    if (tid == 0) {
        float l[8];
        #pragma unroll
        for (int e = 0; e < 8; e++) l[e] = pl[0][e] + pl[1][e] + pl[2][e] + pl[3][e] + rb[e];
        int e0 = 0; float v0 = l[0];
        for (int e = 1; e < 8; e++) if (l[e] > v0) { v0 = l[e]; e0 = e; }
        int e1 = (e0 == 0) ? 1 : 0; float v1 = l[e1];
        for (int e = 0; e < 8; e++) if (e != e0 && l[e] > v1) { v1 = l[e]; e1 = e; }
        float ex = expf(v1 - v0);
        float w0 = 1.f / (1.f + ex);
        float w1 = ex * w0;
        int p0 = atomicAdd(&counts[e0], 1);
        tok_slot[e0 * T_TOK + p0] = (t << 1);
        int p1 = atomicAdd(&counts[e1], 1);
        tok_slot[e1 * T_TOK + p1] = (t << 1) | 1;
        wslot[t * 2]     = w0;
        wslot[t * 2 + 1] = w1;
    }
}

// K2: tiny exclusive prefix over 8 expert counts
__global__ void prefix_kernel(const int* __restrict__ counts, int* __restrict__ offs)
{
    if (threadIdx.x == 0) {
        int a = 0;
        for (int e = 0; e < 8; e++) { offs[e] = a; a += counts[e]; }
    }
}

// ---------------------------------------------------------------------------
// K3: build compacted per-expert A matrix: Agath[off[e]+pos][d] =
//     bf16( xhat[t][d]*ln_g[e][d] + ln_b[e][d] ), plus rowinfo for scatter.
// ---------------------------------------------------------------------------
__global__ __launch_bounds__(256) void gather_kernel(
    const unsigned short* __restrict__ xhat,
    const float* __restrict__ lng, const float* __restrict__ lnb,
    const int* __restrict__ counts, const int* __restrict__ offs,
    const int* __restrict__ tok_slot,
    unsigned short* __restrict__ Agath, int* __restrict__ rowinfo)
{
    const int e = blockIdx.y, pos = blockIdx.x;
    if (pos >= counts[e]) return;
    const int grow = offs[e] + pos;
    const int info = tok_slot[e * T_TOK + pos];
    if (threadIdx.x == 0) rowinfo[grow] = info;
    const int t = info >> 1;
    const int d = threadIdx.x * 4;
    ushort4 hx = *(const ushort4*)(xhat + (size_t)t * DDIM + d);
    float4 g = *(const float4*)(lng + (size_t)e * DDIM + d);
    float4 b = *(const float4*)(lnb + (size_t)e * DDIM + d);
    ushort4 o = { f2bf(bf2f(hx.x) * g.x + b.x),
                  f2bf(bf2f(hx.y) * g.y + b.y),
                  f2bf(bf2f(hx.z) * g.z + b.z),
                  f2bf(bf2f(hx.w) * g.w + b.w) };
    *(ushort4*)(Agath + (size_t)grow * DDIM + d) = o;
}

// ---------------------------------------------------------------------------
// K4: transpose+convert weights: W [E][Kd][Nd] fp32 -> WT [E][Nd][Kd] bf16.
// Block = 256 threads, tile = 256 n-cols x 64 k-rows. Reads coalesced along n
// (1KB/row-pass); each thread then owns one full 128B output line.
// ---------------------------------------------------------------------------
__global__ __launch_bounds__(256) void transpose_kernel(
    const float* __restrict__ W, unsigned short* __restrict__ WT,
    int Kd, int Nd)
{
    const int e  = blockIdx.z;
    const int k0 = blockIdx.y * 64;
    const int n  = blockIdx.x * 256 + threadIdx.x;
    const float* src = W + (size_t)e * Kd * Nd + (size_t)k0 * Nd + n;
    unsigned short* dst = WT + ((size_t)e * Nd + n) * Kd + k0;
    unsigned short buf[64];
    #pragma unroll
    for (int j = 0; j < 64; j++)
        buf[j] = f2bf(src[(size_t)j * Nd]);
    #pragma unroll
    for (int c = 0; c < 8; c++)
        *(int4*)(dst + c * 8) = *(const int4*)(buf + c * 8);
}

// ---------------------------------------------------------------------------
// GEMM, 2-phase prefetch (catalog T3 minimum recipe):
//   prologue: stage tile0 -> buf0; vmcnt(0)+barrier
//   loop t:   issue stage(tile t+1 -> buf cur^1)   [async, in flight]
//             ds_read + 32 MFMA on buf cur          [hides HBM latency]
//             barrier (compiler drains vmcnt(0))    [tile t+1 resident]
// C tile 128x128, BK=64, 4 waves x (64x64), double-buffered LDS (64 KB).
// A [*][Kd] bf16 rows, B = WT [E][Nd][Kd] bf16 rows, global_load_lds w=16.
// EPI=0: +b1, exact GELU -> H (bf16). EPI=1: +b2, *combine-w, atomicAdd out.
// ---------------------------------------------------------------------------
template<int EPI>
__global__ __launch_bounds__(256) void gemm_kernel(
    const unsigned short* __restrict__ Asrc,
    const unsigned short* __restrict__ Bsrc,
    const float* __restrict__ bias,
    const int* __restrict__ counts,
    const int* __restrict__ offs,
    const int* __restrict__ rowinfo,
    const float* __restrict__ wslot,
    unsigned short* __restrict__ Hout,
    float* __restrict__ Out,
    int Kd, int Nd)
{
    const int e  = blockIdx.z;
    const int ne = counts[e];
    const int mt = blockIdx.y;
    if (mt * 128 >= ne) return;
    const int n0 = blockIdx.x * 128;
    const int growbase = offs[e] + mt * 128;
    const int tid  = threadIdx.x;
    const int lane = tid & 63;
    const int wm = (tid >> 7) & 1;
    const int wn = (tid >> 6) & 1;

    __shared__ unsigned short As[2][128 * 64];   // 2 x 16 KB
    __shared__ unsigned short Bs[2][128 * 64];   // 2 x 16 KB

    f32x4 acc[4][4];
    #pragma unroll
    for (int i = 0; i < 4; i++)
        #pragma unroll
        for (int j = 0; j < 4; j++)
            acc[i][j] = (f32x4){0.f, 0.f, 0.f, 0.f};

    // staging: thread tid covers (row = c*32 + tid/8, kchunk = tid%8)
    const unsigned short* ap = Asrc + (size_t)(growbase + (tid >> 3)) * Kd + (tid & 7) * 8;
    const unsigned short* bp = Bsrc + ((size_t)e * Nd + n0 + (tid >> 3)) * Kd + (tid & 7) * 8;
    const size_t rowstep = (size_t)32 * Kd;
    char* const aw = (char*)As + (tid >> 6) * 1024;   // wave-uniform LDS base
    char* const bw = (char*)Bs + (tid >> 6) * 1024;

    // ---- prologue: stage tile 0 into buffer 0 ----
    #pragma unroll
    for (int c = 0; c < 4; c++) {
        GLOAD16(ap + c * rowstep, aw + c * 4096);
        GLOAD16(bp + c * rowstep, bw + c * 4096);
    }
    ap += 64; bp += 64;
    __syncthreads();            // compiler drains vmcnt(0): tile 0 resident

    const int nt = Kd >> 6;
    int cur = 0;
    for (int t = 0; t < nt; ++t) {
        // issue next tile's loads into the other buffer (stays in flight
        // across the compute phase below)
        if (t + 1 < nt) {
            const int nxt = (cur ^ 1) * 16384;   // byte offset of other buffer
            #pragma unroll
            for (int c = 0; c < 4; c++) {
                GLOAD16(ap + c * rowstep, aw + nxt + c * 4096);
                GLOAD16(bp + c * rowstep, bw + nxt + c * 4096);
            }
            ap += 64; bp += 64;
        }
        // compute on current buffer
        const char* Ab = (const char*)As + cur * 16384;
        const char* Bb = (const char*)Bs + cur * 16384;
        #pragma unroll
        for (int kk = 0; kk < 2; kk++) {
            bfrag av[4], bv[4];
            #pragma unroll
            for (int i = 0; i < 4; i++)
                av[i] = *(const bfrag*)(Ab +
                         (wm * 64 + i * 16 + (lane & 15)) * 128 + kk * 64 + ((lane >> 4) << 4));
            #pragma unroll
            for (int j = 0; j < 4; j++)
                bv[j] = *(const bfrag*)(Bb +
                         (wn * 64 + j * 16 + (lane & 15)) * 128 + kk * 64 + ((lane >> 4) << 4));
            #pragma unroll
            for (int i = 0; i < 4; i++)
                #pragma unroll
                for (int j = 0; j < 4; j++)
                    acc[i][j] = __builtin_amdgcn_mfma_f32_16x16x32_bf16(av[i], bv[j], acc[i][j], 0, 0, 0);
        }
        // one barrier per K-step: drains vmcnt(0) (next tile resident) and
        // guarantees all waves finished reading buf[cur] before it is
        // overwritten as the prefetch target of the next iteration.
        __syncthreads();
        cur ^= 1;
    }

    // ---- epilogue (C/D layout: col = lane&15, row = (lane>>4)*4 + reg) ----
    const float* bg = bias + (size_t)e * Nd;
    #pragma unroll
    for (int i = 0; i < 4; i++) {
        #pragma unroll
        for (int r = 0; r < 4; r++) {
            int mrow = wm * 64 + i * 16 + ((lane >> 4) << 2) + r;
            int pos = mt * 128 + mrow;
            if (pos >= ne) continue;
            if constexpr (EPI == 0) {
                size_t rowoff = (size_t)(growbase + mrow) * Nd;
                #pragma unroll
                for (int j = 0; j < 4; j++) {
                    int col = n0 + wn * 64 + j * 16 + (lane & 15);
                    float y = acc[i][j][r] + bg[col];
                    float gl = 0.5f * y * (1.f + erff(y * 0.70710678118654752f));
                    Hout[rowoff + col] = f2bf(gl);
                }
            } else {
                int info = rowinfo[growbase + mrow];
                float wg = wslot[info];
                float* op = Out + (size_t)(info >> 1) * Nd;
                #pragma unroll
                for (int j = 0; j < 4; j++) {
                    int col = n0 + wn * 64 + j * 16 + (lane & 15);
                    float y = acc[i][j][r] + bg[col];
                    atomicAdd(op + col, wg * y);   // exactly 2 adds/elem -> deterministic
                }
            }
        }
    }
}

// ---------------------------------------------------------------------------
extern "C" void kernel_launch(void* const* d_in, const int* in_sizes, int n_in,
                              void* d_out, int out_size, void* d_ws, size_t ws_size,
                              hipStream_t stream)
{
    (void)in_sizes; (void)n_in;
    const float* hidden   = (const float*)d_in[0];
    const float* rn_g     = (const float*)d_in[1];
    const float* rn_b     = (const float*)d_in[2];
    const float* router_w = (const float*)d_in[3];
    const float* router_b = (const float*)d_in[4];
    const float* ln_g     = (const float*)d_in[5];
    const float* ln_b     = (const float*)d_in[6];
    const float* w1       = (const float*)d_in[7];
    const float* b1       = (const float*)d_in[8];
    const float* w2       = (const float*)d_in[9];
    const float* b2       = (const float*)d_in[10];
    float* out = (float*)d_out;

    // workspace layout (bytes), total ~160.9 MB
    //   xhat   @ 0           :  8,388,608  (4096 x 1024 bf16)
    //   Agath  @ 8,388,608   : 17,039,360  (8320 x 1024 bf16)
    //   H      @ 25,427,968  : 68,157,440  (8320 x 4096 bf16)
    //   WT     @ 93,585,408  : 67,108,864  (W1T, then reused for W2T)
    //   counts @ 160,694,272 / offs / tok_slot / rowinfo / wslot
    char* ws = (char*)d_ws;
    unsigned short* xhat   = (unsigned short*)ws;
    unsigned short* Agath  = (unsigned short*)(ws + 8388608);
    unsigned short* H      = (unsigned short*)(ws + 25427968);
    unsigned short* WT     = (unsigned short*)(ws + 93585408);
    int*   counts   = (int*)(ws + 160694272);
    int*   offs     = (int*)(ws + 160694304);
    int*   tok_slot = (int*)(ws + 160694336);
    int*   rowinfo  = (int*)(ws + 160825408);
    float* wslot    = (float*)(ws + 160858688);
    if (ws_size < 160891456) return;   // fail loudly (validation will catch it)

    hipMemsetAsync(counts, 0, 64, stream);                 // counts + offs
    hipMemsetAsync(d_out, 0, (size_t)out_size * sizeof(float), stream);

    // W1 [8][1024][4096] -> W1T [8][4096][1024]
    transpose_kernel<<<dim3(IDIM / 256, DDIM / 64, NEXP), 256, 0, stream>>>(w1, WT, DDIM, IDIM);
    router_kernel<<<T_TOK, 256, 0, stream>>>(hidden, rn_g, rn_b, router_w, router_b,
                                             xhat, counts, tok_slot, wslot);
    prefix_kernel<<<1, 64, 0, stream>>>(counts, offs);
    gather_kernel<<<dim3(T_TOK, NEXP), 256, 0, stream>>>(xhat, ln_g, ln_b, counts, offs,
                                                         tok_slot, Agath, rowinfo);
    // GEMM1: [rows x 1024] x [1024 x 4096] + b1, GELU -> H
    gemm_kernel<0><<<dim3(IDIM / 128, 32, NEXP), 256, 0, stream>>>(
        Agath, WT, b1, counts, offs, rowinfo, wslot, H, nullptr, DDIM, IDIM);
    // W2 [8][4096][1024] -> W2T [8][1024][4096] (reuses WT buffer after GEMM1)
    transpose_kernel<<<dim3(DDIM / 256, IDIM / 64, NEXP), 256, 0, stream>>>(w2, WT, IDIM, DDIM);
    // GEMM2: [rows x 4096] x [4096 x 1024] + b2, *w, scatter-add -> out
    gemm_kernel<1><<<dim3(DDIM / 128, 32, NEXP), 256, 0, stream>>>(
        H, WT, b2, counts, offs, rowinfo, wslot, nullptr, out, IDIM, DDIM);
}